// Round 23
// baseline (111.099 us; speedup 1.0000x reference)
//
#include <hip/hip_runtime.h>
#include <hip/hip_bf16.h>

#define BATCH 16
#define SEQ   2048
#define HD    128
#define TB    64            // proj tile rows
#define QB2   128           // attn q-tile rows
#define KB2   128           // attn kv-tile rows
#define NTB   (SEQ/KB2)     // 16 kv tiles per batch
#define PLANE ((size_t)BATCH*SEQ*HD)   // shorts per ws plane

typedef __attribute__((ext_vector_type(8)))  short bf16x8;
typedef __attribute__((ext_vector_type(4)))  float f32x4;
typedef __attribute__((ext_vector_type(16))) float f32x16;

#define MFMA(a,b,c)   __builtin_amdgcn_mfma_f32_16x16x32_bf16(a,b,c,0,0,0)
#define MFMA32(a,b,c) __builtin_amdgcn_mfma_f32_32x32x16_bf16(a,b,c,0,0,0)

__device__ __forceinline__ short f2bf(float f){
  union{float f; unsigned u;} v; v.f = f;
  unsigned r = (v.u + 0x7FFFu + ((v.u>>16)&1u))>>16;
  return (short)r;
}
__device__ __forceinline__ unsigned packbf(float lo, float hi){
  return ((unsigned)(unsigned short)f2bf(hi) << 16) | (unsigned short)f2bf(lo);
}
__device__ __forceinline__ bf16x8 pack8(f32x4 a, f32x4 b){
  bf16x8 r;
  r[0]=f2bf(a[0]); r[1]=f2bf(a[1]); r[2]=f2bf(a[2]); r[3]=f2bf(a[3]);
  r[4]=f2bf(b[0]); r[5]=f2bf(b[1]); r[6]=f2bf(b[2]); r[7]=f2bf(b[3]);
  return r;
}
__device__ __forceinline__ bf16x8 ldfrag(const float* base, size_t eo){
  const float* p = base + eo;
  return pack8(*(const f32x4*)p, *(const f32x4*)(p+4));
}
__device__ __forceinline__ bf16x8 mkfrag(unsigned w0, unsigned w1,
                                         unsigned w2, unsigned w3){
  union{ unsigned u[4]; bf16x8 v; } t;
  t.u[0]=w0; t.u[1]=w1; t.u[2]=w2; t.u[3]=w3;
  return t.v;
}

// ---------------- kernel 0: W fp32 -> bf16 once ------------------------------
__global__ __launch_bounds__(256)
void wconv_kernel(const float* __restrict__ Wq, const float* __restrict__ Wk,
                  const float* __restrict__ Wv, short* __restrict__ wb)
{
  int i = (blockIdx.x*256 + threadIdx.x)*8;
  const float* src = (i < 16384) ? Wq : (i < 32768 ? Wk : Wv);
  int off = i & 16383;
  f32x4 a = *(const f32x4*)(src + off);
  f32x4 b = *(const f32x4*)(src + off + 4);
  *(bf16x8*)(wb + i) = pack8(a, b);
}

// ---------------- kernel 1: projections -> ws (bf16) -------------------------
// z=0: Qh row-major. z=1: Kh 32KB images [128 rows]: chunk(r,c8)=r*16+(c8^(r&7)).
// z=2: Vh^T 32KB images [d][c8 0..15]: chunk(d,c8)=d*16+(c8^(d&7)).
__global__ __launch_bounds__(256)
void proj_kernel(const float* __restrict__ q, const float* __restrict__ k,
                 const float* __restrict__ v,
                 const float* __restrict__ bq, const float* __restrict__ bk,
                 const float* __restrict__ bv,
                 const short* __restrict__ wb, short* __restrict__ ws)
{
  __shared__ __align__(16) short T[TB*136];    // [s_local][h] bounce (z<2)
  __shared__ __align__(16) short VT[HD*72];    // [h][s_local] bounce (z==2)

  const int z = blockIdx.y;
  const float* x  = z==0 ? q  : (z==1 ? k  : v);
  const float* bb = z==0 ? bq : (z==1 ? bk : bv);
  const short* W  = wb + (size_t)z*HD*HD;

  const int tid = threadIdx.x;
  const int w = tid>>6, l = tid&63, li = l&15, g = l>>4;
  const int bx = blockIdx.x;                   // 64-row tile id (b = bx>>5)
  const int rowbase = bx*TB + w*16;

  bf16x8 afr[4];
  const float* xr = x + (size_t)(rowbase+li)*HD + g*8;
  #pragma unroll
  for (int ks=0; ks<4; ks++) afr[ks] = ldfrag(xr, (size_t)ks*32);

  f32x4 acc[8];
  #pragma unroll
  for (int ct=0; ct<8; ct++) acc[ct] = (f32x4){0.f,0.f,0.f,0.f};
  #pragma unroll
  for (int ct=0; ct<8; ct++){
    #pragma unroll
    for (int ks=0; ks<4; ks++){
      bf16x8 bfr = *(const bf16x8*)(W + (size_t)(ct*16+li)*HD + ks*32 + g*8);
      acc[ct] = MFMA(afr[ks], bfr, acc[ct]);
    }
  }

  const int img  = (bx>>1);                    // 128-row image id
  const int half = bx & 1;                     // which 64-row half

  if (z < 2){
    #pragma unroll
    for (int ct=0; ct<8; ct++){
      float bias = bb[ct*16+li];
      #pragma unroll
      for (int r=0; r<4; r++)
        T[(w*16+g*4+r)*136 + ct*16+li] = f2bf(acc[ct][r] + bias);
    }
    __syncthreads();
    if (z == 0){
      short* dst = ws + (size_t)bx*TB*HD;
      #pragma unroll
      for (int it=0; it<4; it++){
        int c = tid + it*256, row = c>>4, c8 = c&15;
        *(bf16x8*)(dst + row*HD + c8*8) = *(const bf16x8*)&T[row*136 + c8*8];
      }
    } else {
      short* dst = ws + PLANE + (size_t)img*16384;
      #pragma unroll
      for (int it=0; it<4; it++){
        int c = tid + it*256, row = c>>4, c8 = c&15;
        int r128 = half*64 + row;
        int chunk = r128*16 + (c8 ^ (r128&7));
        *(bf16x8*)(dst + chunk*8) = *(const bf16x8*)&T[row*136 + c8*8];
      }
    }
  } else {
    #pragma unroll
    for (int ct=0; ct<8; ct++){
      float bias = bb[ct*16+li];
      #pragma unroll
      for (int r=0; r<4; r++)
        VT[(ct*16+li)*72 + w*16+g*4+r] = f2bf(acc[ct][r] + bias);
    }
    __syncthreads();
    short* dst = ws + 2*PLANE + (size_t)img*16384;
    const int d = tid>>1, hf = tid&1;
    #pragma unroll
    for (int j=0; j<4; j++){
      int c8l = hf*4 + j;
      int c8g = half*8 + c8l;
      int chunk = d*16 + (c8g ^ (d&7));
      *(bf16x8*)(dst + chunk*8) = *(const bf16x8*)&VT[d*72 + c8l*8];
    }
  }
}

// ---------------- kernel 2: causal flash attention (32x32, decoupled) --------
// 8 waves = 4 q-strips x 2 k-halves. Each wave keeps an INDEPENDENT online
// softmax (m,l,O) over its own k-half for the whole loop (valid: online
// softmax over a partition); merge once in epilogue with e^{m_h-M} weights.
// -> only ONE block-wide barrier per iteration (buffer swap). Rescale factors
// are own-wave (16 __shfl, no LDS). P assembly identical to R22 (verified).
__global__ __launch_bounds__(512, 2)
void attn_kernel(const short* __restrict__ ws, float* __restrict__ out)
{
  __shared__ __align__(16) short KVL[2][32768]; // [buf][K 32KB | V 32KB]
  __shared__ float sm[4][2][2][32];             // [strip][h][{m,l}][q] (epilogue)

  const int bid  = blockIdx.x;                  // 256 blocks
  const int xcd  = bid & 7, slot = bid >> 3;
  const int b    = xcd*2 + (slot >> 4);
  const int qt   = slot & 15;

  const int tid = threadIdx.x;
  const int w = tid>>6, l = tid&63;
  const int s = w & 3, h = w >> 2;              // q-strip, k-half
  const int lq = l & 31, h5 = l >> 5;

  const short* Qw    = ws;
  const short* KimgB = ws + PLANE   + (size_t)b*NTB*16384;
  const short* VimgB = ws + 2*PLANE + (size_t)b*NTB*16384;

  const size_t qbase = (size_t)b*SEQ + qt*QB2;
  const float sc = 0.088388347648318447f;       // 1/sqrt(128)
  const int qloc = s*32 + lq;                   // q row within tile

  // Q fragments: B-operand (d16 x q32): lane: q=lq, d = ks*16 + h5*8 + j
  bf16x8 qfr[8];
  #pragma unroll
  for (int ks=0; ks<8; ks++)
    qfr[ks] = *(const bf16x8*)&Qw[(qbase + s*32 + lq)*HD + ks*16 + h5*8];

  f32x16 oacc[4];
  #pragma unroll
  for (int db=0; db<4; db++) oacc[db] = (f32x16)(0.f);
  float m_run = -1e30f, l_run = 0.f;            // own-half online softmax

  bf16x8 stg[8];
  #define LOADT(kt_) do{                                                    \
    const short* sK = KimgB + (size_t)(kt_)*16384;                          \
    const short* sV = VimgB + (size_t)(kt_)*16384;                          \
    _Pragma("unroll")                                                       \
    for (int j=0;j<4;j++) stg[j]   = *(const bf16x8*)(sK + (tid + j*512)*8);\
    _Pragma("unroll")                                                       \
    for (int j=0;j<4;j++) stg[4+j] = *(const bf16x8*)(sV + (tid + j*512)*8);\
  }while(0)
  #define WRT(nb_) do{                                                     \
    short* dK = &KVL[nb_][0];                                              \
    short* dV = &KVL[nb_][16384];                                          \
    _Pragma("unroll")                                                      \
    for (int j=0;j<4;j++) *(bf16x8*)(dK + (tid+j*512)*8) = stg[j];         \
    _Pragma("unroll")                                                      \
    for (int j=0;j<4;j++) *(bf16x8*)(dV + (tid+j*512)*8) = stg[4+j];       \
  }while(0)

  LOADT(0); WRT(0); __syncthreads();
  int cur = 0;

  for (int kt=0; kt<=qt; kt++){
    const bool pre = (kt < qt);
    if (pre) LOADT(kt+1);

    const short* KL = &KVL[cur][0];
    const short* VL = &KVL[cur][16384];

    // ---- QK^T: S[k 64(own half)][q 32(strip)]
    f32x16 sacc[2];
    sacc[0] = (f32x16)(0.f); sacc[1] = (f32x16)(0.f);
    __builtin_amdgcn_s_setprio(1);
    #pragma unroll
    for (int ct=0; ct<2; ct++){
      const int r = h*64 + ct*32 + lq;          // K row
      #pragma unroll
      for (int ks=0; ks<8; ks++){
        const int chunk = r*16 + ((2*ks + h5) ^ (r&7));
        bf16x8 kfr = *(const bf16x8*)&KL[chunk*8];
        sacc[ct] = MFMA32(kfr, qfr[ks], sacc[ct]);
      }
    }
    __builtin_amdgcn_s_setprio(0);

    // ---- own-half online softmax (no cross-wave merge)
    float sv[2][16];
    float pm = -1e30f;
    const bool diag = (kt == qt);
    #pragma unroll
    for (int ct=0; ct<2; ct++){
      #pragma unroll
      for (int r=0; r<16; r++){
        float x = sacc[ct][r]*sc;
        if (diag){
          int k_loc = h*64 + ct*32 + (r&3) + 8*(r>>2) + 4*h5;
          if (k_loc > qloc) x = -1e30f;
        }
        sv[ct][r] = x;
        pm = fmaxf(pm, x);
      }
    }
    pm = fmaxf(pm, __shfl_xor(pm, 32));
    float m_new = fmaxf(m_run, pm);
    float sclq  = __expf(m_run - m_new);
    m_run = m_new;
    float psum = 0.f;
    #pragma unroll
    for (int ct=0; ct<2; ct++){
      #pragma unroll
      for (int r=0; r<16; r++){
        float p = __expf(sv[ct][r] - m_new);
        sv[ct][r] = p;
        psum += p;
      }
    }
    psum += __shfl_xor(psum, 32);
    l_run = l_run*sclq + psum;

    // ---- O rescale: factor for q=qr pulled from own wave via shfl
    #pragma unroll
    for (int db=0; db<4; db++){
      #pragma unroll
      for (int r=0; r<16; r++){
        float f = __shfl(sclq, (r&3) + 8*(r>>2) + 4*h5);
        oacc[db][r] *= f;
      }
    }

    // ---- P -> bf16 A-frags in registers (identical winding to R22)
    __builtin_amdgcn_s_setprio(1);
    #pragma unroll
    for (int ct=0; ct<2; ct++){
      unsigned G[4][2], GX[4][2];
      #pragma unroll
      for (int g2=0; g2<4; g2++){
        #pragma unroll
        for (int p=0; p<2; p++)
          G[g2][p] = packbf(sv[ct][g2*4+2*p], sv[ct][g2*4+2*p+1]);
      }
      #pragma unroll
      for (int g2=0; g2<4; g2++){
        #pragma unroll
        for (int p=0; p<2; p++)
          GX[g2][p] = __shfl_xor((int)G[g2][p], 32);
      }
      bf16x8 pf0 = h5 ? mkfrag(GX[1][0],GX[1][1],G[1][0],G[1][1])
                      : mkfrag(G[0][0],G[0][1],GX[0][0],GX[0][1]);
      bf16x8 pf1 = h5 ? mkfrag(GX[3][0],GX[3][1],G[3][0],G[3][1])
                      : mkfrag(G[2][0],G[2][1],GX[2][0],GX[2][1]);
      // ---- PV: A=P(32q x16k), B=V(16k x32d)
      #pragma unroll
      for (int ksp=0; ksp<2; ksp++){
        bf16x8 pf = ksp ? pf1 : pf0;
        #pragma unroll
        for (int db=0; db<4; db++){
          const int d = db*32 + lq;
          const int c8 = h*8 + ct*4 + ksp*2 + h5;
          const int chunk = d*16 + (c8 ^ (d&7));
          bf16x8 vfr = *(const bf16x8*)&VL[chunk*8];
          oacc[db] = MFMA32(pf, vfr, oacc[db]);
        }
      }
    }
    __builtin_amdgcn_s_setprio(0);

    if (pre) WRT(cur^1);
    __syncthreads();                            // single barrier per iteration
    cur ^= 1;
  } // kt

  // ---- epilogue: merge the two k-half partials per strip -------------------
  if (l < 32){ sm[s][h][0][lq] = m_run; sm[s][h][1][lq] = l_run; }
  __syncthreads();
  float m_p = sm[s][h^1][0][lq];
  float M   = fmaxf(m_run, m_p);
  float sfac = __expf(m_run - M);               // own-O weight (q=lq)

  float* Obuf = (float*)&KVL[0][0];             // KV buffers free now
  if (h == 1){
    #pragma unroll
    for (int db=0; db<4; db++){
      #pragma unroll
      for (int r=0; r<16; r++){
        int qr = (r&3) + 8*(r>>2) + 4*h5;
        float fw = __shfl(sfac, qr);
        Obuf[s*4096 + qr*128 + db*32 + lq] = oacc[db][r]*fw;
      }
    }
  }
  __syncthreads();
  if (h == 0){
    #pragma unroll
    for (int db=0; db<4; db++){
      #pragma unroll
      for (int r=0; r<16; r++){
        int qr = (r&3) + 8*(r>>2) + 4*h5;
        float m0 = sm[s][0][0][qr], l0 = sm[s][0][1][qr];
        float m1 = sm[s][1][0][qr], l1 = sm[s][1][1][qr];
        float Mq = fmaxf(m0, m1);
        float lt = l0*__expf(m0-Mq) + l1*__expf(m1-Mq);
        float fw = __shfl(sfac, qr);
        float o = (oacc[db][r]*fw + Obuf[s*4096 + qr*128 + db*32 + lq]) / lt;
        out[(qbase + s*32 + qr)*HD + db*32 + lq] = o;
      }
    }
  }
  #undef LOADT
  #undef WRT
}

// ---------------- launch -----------------------------------------------------
// d_in = [q, k, v, Wq, bq, Wk, bk, Wv, bv, mask] (confirmed R15).
// ws: Qh | Kimg(32KB x 256) | Vimg | Wbf16 (25.3 MB).
extern "C" void kernel_launch(void* const* d_in, const int* in_sizes, int n_in,
                              void* d_out, int out_size, void* d_ws, size_t ws_size,
                              hipStream_t stream)
{
  short* ws = (short*)d_ws;
  short* wb = ws + 3*PLANE;

  wconv_kernel<<<24, 256, 0, stream>>>(
      (const float*)d_in[3], (const float*)d_in[5], (const float*)d_in[7], wb);

  dim3 pg(BATCH*SEQ/TB, 3);
  proj_kernel<<<pg, 256, 0, stream>>>(
      (const float*)d_in[0], (const float*)d_in[1], (const float*)d_in[2],
      (const float*)d_in[4], (const float*)d_in[6], (const float*)d_in[8],
      wb, ws);

  attn_kernel<<<dim3(BATCH*NTB), 512, 0, stream>>>(ws, (float*)d_out);
}

// Round 24
// 99.426 us; speedup vs baseline: 1.1174x; 1.1174x over previous
//
#include <hip/hip_runtime.h>
#include <hip/hip_bf16.h>

#define BATCH 16
#define SEQ   2048
#define HD    128
#define TB    64            // proj tile rows
#define QB3   64            // attn q-tile rows
#define KB3   64            // attn kv-tile rows
#define NT3   (SEQ/QB3)     // 32 q-tiles per batch
#define PLANE ((size_t)BATCH*SEQ*HD)   // shorts per ws plane

typedef __attribute__((ext_vector_type(8))) short bf16x8;
typedef __attribute__((ext_vector_type(4))) float f32x4;
typedef __attribute__((ext_vector_type(2))) unsigned int u32x2;

#define MFMA(a,b,c) __builtin_amdgcn_mfma_f32_16x16x32_bf16(a,b,c,0,0,0)

__device__ __forceinline__ short f2bf(float f){
  union{float f; unsigned u;} v; v.f = f;
  unsigned r = (v.u + 0x7FFFu + ((v.u>>16)&1u))>>16;
  return (short)r;
}
__device__ __forceinline__ unsigned packbf(float lo, float hi){
  return ((unsigned)(unsigned short)f2bf(hi) << 16) | (unsigned short)f2bf(lo);
}
__device__ __forceinline__ bf16x8 pack8(f32x4 a, f32x4 b){
  bf16x8 r;
  r[0]=f2bf(a[0]); r[1]=f2bf(a[1]); r[2]=f2bf(a[2]); r[3]=f2bf(a[3]);
  r[4]=f2bf(b[0]); r[5]=f2bf(b[1]); r[6]=f2bf(b[2]); r[7]=f2bf(b[3]);
  return r;
}
__device__ __forceinline__ bf16x8 ldfrag(const float* base, size_t eo){
  const float* p = base + eo;
  return pack8(*(const f32x4*)p, *(const f32x4*)(p+4));
}

// ---------------- kernel 0: W fp32 -> bf16 once ------------------------------
__global__ __launch_bounds__(256)
void wconv_kernel(const float* __restrict__ Wq, const float* __restrict__ Wk,
                  const float* __restrict__ Wv, short* __restrict__ wb)
{
  int i = (blockIdx.x*256 + threadIdx.x)*8;
  const float* src = (i < 16384) ? Wq : (i < 32768 ? Wk : Wv);
  int off = i & 16383;
  f32x4 a = *(const f32x4*)(src + off);
  f32x4 b = *(const f32x4*)(src + off + 4);
  *(bf16x8*)(wb + i) = pack8(a, b);
}

// ---------------- kernel 1: projections -> ws (bf16) -------------------------
// z=0: Qh row-major. z=1: Kh 32KB images [128 rows]: chunk(r,c8)=r*16+(c8^(r&7)).
// z=2: Vh^T 32KB images [d][c8 0..15]: chunk(d,c8)=d*16+(c8^(d&7)).
// A 64-row KV sub-tile = K: contiguous half-image; V: bit-3 of chunk selects half.
__global__ __launch_bounds__(256)
void proj_kernel(const float* __restrict__ q, const float* __restrict__ k,
                 const float* __restrict__ v,
                 const float* __restrict__ bq, const float* __restrict__ bk,
                 const float* __restrict__ bv,
                 const short* __restrict__ wb, short* __restrict__ ws)
{
  __shared__ __align__(16) short T[TB*136];    // [s_local][h] bounce (z<2)
  __shared__ __align__(16) short VT[HD*72];    // [h][s_local] bounce (z==2)

  const int z = blockIdx.y;
  const float* x  = z==0 ? q  : (z==1 ? k  : v);
  const float* bb = z==0 ? bq : (z==1 ? bk : bv);
  const short* W  = wb + (size_t)z*HD*HD;

  const int tid = threadIdx.x;
  const int w = tid>>6, l = tid&63, li = l&15, g = l>>4;
  const int bx = blockIdx.x;                   // 64-row tile id (b = bx>>5)
  const int rowbase = bx*TB + w*16;

  bf16x8 afr[4];
  const float* xr = x + (size_t)(rowbase+li)*HD + g*8;
  #pragma unroll
  for (int ks=0; ks<4; ks++) afr[ks] = ldfrag(xr, (size_t)ks*32);

  f32x4 acc[8];
  #pragma unroll
  for (int ct=0; ct<8; ct++) acc[ct] = (f32x4){0.f,0.f,0.f,0.f};
  #pragma unroll
  for (int ct=0; ct<8; ct++){
    #pragma unroll
    for (int ks=0; ks<4; ks++){
      bf16x8 bfr = *(const bf16x8*)(W + (size_t)(ct*16+li)*HD + ks*32 + g*8);
      acc[ct] = MFMA(afr[ks], bfr, acc[ct]);
    }
  }

  const int img  = (bx>>1);                    // 128-row image id
  const int half = bx & 1;                     // which 64-row half

  if (z < 2){
    #pragma unroll
    for (int ct=0; ct<8; ct++){
      float bias = bb[ct*16+li];
      #pragma unroll
      for (int r=0; r<4; r++)
        T[(w*16+g*4+r)*136 + ct*16+li] = f2bf(acc[ct][r] + bias);
    }
    __syncthreads();
    if (z == 0){
      short* dst = ws + (size_t)bx*TB*HD;
      #pragma unroll
      for (int it=0; it<4; it++){
        int c = tid + it*256, row = c>>4, c8 = c&15;
        *(bf16x8*)(dst + row*HD + c8*8) = *(const bf16x8*)&T[row*136 + c8*8];
      }
    } else {
      short* dst = ws + PLANE + (size_t)img*16384;
      #pragma unroll
      for (int it=0; it<4; it++){
        int c = tid + it*256, row = c>>4, c8 = c&15;
        int r128 = half*64 + row;
        int chunk = r128*16 + (c8 ^ (r128&7));
        *(bf16x8*)(dst + chunk*8) = *(const bf16x8*)&T[row*136 + c8*8];
      }
    }
  } else {
    #pragma unroll
    for (int ct=0; ct<8; ct++){
      float bias = bb[ct*16+li];
      #pragma unroll
      for (int r=0; r<4; r++)
        VT[(ct*16+li)*72 + w*16+g*4+r] = f2bf(acc[ct][r] + bias);
    }
    __syncthreads();
    short* dst = ws + 2*PLANE + (size_t)img*16384;
    const int d = tid>>1, hf = tid&1;
    #pragma unroll
    for (int j=0; j<4; j++){
      int c8l = hf*4 + j;
      int c8g = half*8 + c8l;
      int chunk = d*16 + (c8g ^ (d&7));
      *(bf16x8*)(dst + chunk*8) = *(const bf16x8*)&VT[d*72 + c8l*8];
    }
  }
}

// ---------------- kernel 2: causal flash attention ---------------------------
// R21 structure (swapped QK^T, lane-local softmax, 1 barrier/iter) shrunk to
// 256-thread blocks / 64-row tiles: LDS 73.2KB -> 2 blocks/CU co-resident
// (latency hiding across independent blocks). CU-paired qt for balance.
__global__ __launch_bounds__(256, 2)
void attn_kernel(const short* __restrict__ ws, float* __restrict__ out)
{
  __shared__ __align__(16) short KVL[2][16384]; // [buf][K 8192 | V 8192] shorts
  __shared__ __align__(16) short PL[4][16*72];  // per-wave P, padded

  const int bid  = blockIdx.x;                  // 512 blocks
  const int xcd  = bid & 7, slot = bid >> 3;    // slot 0..63
  const int b    = xcd*2 + (slot >> 5);
  const int sl   = slot & 31;
  const int qt   = (slot < 32) ? sl : (31 - sl);  // co-resident pair ~33 iters

  const int tid = threadIdx.x;
  const int w = tid>>6, l = tid&63, li = l&15, g = l>>4;

  const short* Qw    = ws;
  const short* KimgB = ws + PLANE   + (size_t)b*(SEQ/128)*16384;
  const short* VimgB = ws + 2*PLANE + (size_t)b*(SEQ/128)*16384;

  const size_t qbase = (size_t)b*SEQ + qt*QB3;
  short* Pw = &PL[w][0];
  const float sc = 0.088388347648318447f;       // 1/sqrt(128)

  bf16x8 qfr[4];
  #pragma unroll
  for (int ks=0; ks<4; ks++)
    qfr[ks] = *(const bf16x8*)&Qw[(qbase + w*16 + li)*HD + ks*32 + g*8];

  f32x4 oacc[8];
  #pragma unroll
  for (int dt=0; dt<8; dt++) oacc[dt] = (f32x4){0.f,0.f,0.f,0.f};
  float mreg = -1e30f, lreg = 0.f;              // for q-row (w*16 + li)

  // staging: K 1024 chunks (16KB), V 1024 chunks; 4+4 per thread (exact)
  bf16x8 stg[8];
  #define LOADT(kt_) do{                                                     \
    const short* sK = KimgB + (size_t)((kt_)>>1)*16384 + ((kt_)&1)*8192;     \
    const short* sV = VimgB + (size_t)((kt_)>>1)*16384;                      \
    const int vh = ((kt_)&1)*8;                                              \
    _Pragma("unroll")                                                        \
    for (int j=0;j<4;j++) stg[j] = *(const bf16x8*)(sK + (tid + j*256)*8);   \
    _Pragma("unroll")                                                        \
    for (int j=0;j<4;j++){                                                   \
      int i = tid + j*256, d = i>>3, c8s = i&7;                              \
      stg[4+j] = *(const bf16x8*)(sV + (d*16 + vh + c8s)*8);                 \
    }                                                                        \
  }while(0)
  #define WRT(nb_) do{                                                      \
    short* dK = &KVL[nb_][0];                                               \
    short* dV = &KVL[nb_][8192];                                            \
    _Pragma("unroll")                                                       \
    for (int j=0;j<4;j++) *(bf16x8*)(dK + (tid+j*256)*8) = stg[j];          \
    _Pragma("unroll")                                                       \
    for (int j=0;j<4;j++) *(bf16x8*)(dV + (tid+j*256)*8) = stg[4+j];        \
  }while(0)

  LOADT(0); WRT(0); __syncthreads();
  int cur = 0;

  for (int kt=0; kt<=qt; kt++){
    const bool pre = (kt < qt);
    if (pre) LOADT(kt+1);

    const short* KL = &KVL[cur][0];
    const short* VL = &KVL[cur][8192];

    // ---- swapped QK^T : lane holds S[q=li][k = ct*16 + g*4 + r], ct<4
    f32x4 st[4];
    #pragma unroll
    for (int ct=0; ct<4; ct++) st[ct] = (f32x4){0.f,0.f,0.f,0.f};
    __builtin_amdgcn_s_setprio(1);
    #pragma unroll
    for (int ct=0; ct<4; ct++){
      const int row = ct*16 + li;               // K row (A-frag)
      #pragma unroll
      for (int ks=0; ks<4; ks++){
        const int chunk = row*16 + ((ks*4 + g) ^ (row&7));
        bf16x8 kfr = *(const bf16x8*)&KL[chunk*8];
        st[ct] = MFMA(kfr, qfr[ks], st[ct]);    // SWAPPED operands
      }
    }
    __builtin_amdgcn_s_setprio(0);

    // ---- lane-local online softmax for q-row (w*16 + li)
    float sv[4][4];
    float pm = -1e30f;
    const bool diag = (kt == qt);
    const int qloc = w*16 + li;
    #pragma unroll
    for (int ct=0; ct<4; ct++){
      #pragma unroll
      for (int r=0; r<4; r++){
        float x = st[ct][r]*sc;
        if (diag && (ct*16 + g*4 + r) > qloc) x = -1e30f;
        sv[ct][r] = x;
        pm = fmaxf(pm, x);
      }
    }
    pm = fmaxf(pm, __shfl_xor(pm, 16));
    pm = fmaxf(pm, __shfl_xor(pm, 32));
    float mn   = fmaxf(mreg, pm);
    float sclq = __expf(mreg - mn);
    mreg = mn;
    float psum = 0.f;
    #pragma unroll
    for (int ct=0; ct<4; ct++){
      #pragma unroll
      for (int r=0; r<4; r++){
        float p = __expf(sv[ct][r] - mn);
        sv[ct][r] = p;
        psum += p;
      }
    }
    psum += __shfl_xor(psum, 16);
    psum += __shfl_xor(psum, 32);
    lreg = lreg*sclq + psum;

    // ---- rescale oacc (rows q = g*4+r: factors live in lanes 0..15)
    float sclo[4];
    #pragma unroll
    for (int r=0; r<4; r++) sclo[r] = __shfl(sclq, g*4 + r);
    #pragma unroll
    for (int dt=0; dt<8; dt++){
      #pragma unroll
      for (int r=0; r<4; r++) oacc[dt][r] *= sclo[r];
    }

    // ---- P -> LDS (4x ds_write_b64), then PV over k 0..63
    #pragma unroll
    for (int c4=0; c4<4; c4++){
      u32x2 pw;
      pw[0] = packbf(sv[c4][0], sv[c4][1]);
      pw[1] = packbf(sv[c4][2], sv[c4][3]);
      *(u32x2*)&Pw[li*72 + c4*16 + g*4] = pw;   // row q=li, k=c4*16+g*4..+3
    }
    __builtin_amdgcn_s_setprio(1);
    #pragma unroll
    for (int ks2=0; ks2<2; ks2++){
      bf16x8 afr = *(const bf16x8*)&Pw[li*72 + ks2*32 + g*8];
      #pragma unroll
      for (int dt=0; dt<8; dt++){
        const int d = dt*16 + li;
        const int chunk = d*8 + ((ks2*4 + g) ^ (d&7));
        bf16x8 bfr = *(const bf16x8*)&VL[chunk*8];
        oacc[dt] = MFMA(afr, bfr, oacc[dt]);
      }
    }
    __builtin_amdgcn_s_setprio(0);

    if (pre) WRT(cur^1);
    __syncthreads();                            // single barrier per iteration
    cur ^= 1;
  } // kt

  // ---- epilogue: fp32 out; lsum for row q=g*4+r from lanes 0..15
  float lso[4];
  #pragma unroll
  for (int r=0; r<4; r++) lso[r] = __shfl(lreg, g*4 + r);
  float* Ob = out + qbase*HD;
  #pragma unroll
  for (int dt=0; dt<8; dt++){
    #pragma unroll
    for (int r=0; r<4; r++){
      Ob[(size_t)(w*16 + g*4 + r)*HD + dt*16 + li] = oacc[dt][r] / lso[r];
    }
  }
  #undef LOADT
  #undef WRT
}

// ---------------- launch -----------------------------------------------------
// d_in = [q, k, v, Wq, bq, Wk, bk, Wv, bv, mask] (confirmed R15).
// ws: Qh | Kimg(32KB x 256) | Vimg | Wbf16 (25.3 MB).
extern "C" void kernel_launch(void* const* d_in, const int* in_sizes, int n_in,
                              void* d_out, int out_size, void* d_ws, size_t ws_size,
                              hipStream_t stream)
{
  short* ws = (short*)d_ws;
  short* wb = ws + 3*PLANE;

  wconv_kernel<<<24, 256, 0, stream>>>(
      (const float*)d_in[3], (const float*)d_in[5], (const float*)d_in[7], wb);

  dim3 pg(BATCH*SEQ/TB, 3);
  proj_kernel<<<pg, 256, 0, stream>>>(
      (const float*)d_in[0], (const float*)d_in[1], (const float*)d_in[2],
      (const float*)d_in[4], (const float*)d_in[6], (const float*)d_in[8],
      wb, ws);

  attn_kernel<<<dim3(BATCH*NT3), 256, 0, stream>>>(ws, (float*)d_out);
}

// Round 25
// 96.244 us; speedup vs baseline: 1.1544x; 1.0331x over previous
//
#include <hip/hip_runtime.h>
#include <hip/hip_bf16.h>

#define BATCH 16
#define SEQ   2048
#define HD    128
#define TB    64            // proj tile rows
#define QB3   64            // attn q-tile rows
#define NT3   (SEQ/QB3)     // 32 q-tiles per batch
#define PLANE ((size_t)BATCH*SEQ*HD)   // shorts per ws plane

typedef __attribute__((ext_vector_type(8))) short bf16x8;
typedef __attribute__((ext_vector_type(4))) float f32x4;
typedef __attribute__((ext_vector_type(2))) unsigned int u32x2;

#define MFMA(a,b,c) __builtin_amdgcn_mfma_f32_16x16x32_bf16(a,b,c,0,0,0)

__device__ __forceinline__ short f2bf(float f){
  union{float f; unsigned u;} v; v.f = f;
  unsigned r = (v.u + 0x7FFFu + ((v.u>>16)&1u))>>16;
  return (short)r;
}
__device__ __forceinline__ unsigned packbf(float lo, float hi){
  return ((unsigned)(unsigned short)f2bf(hi) << 16) | (unsigned short)f2bf(lo);
}
__device__ __forceinline__ bf16x8 pack8(f32x4 a, f32x4 b){
  bf16x8 r;
  r[0]=f2bf(a[0]); r[1]=f2bf(a[1]); r[2]=f2bf(a[2]); r[3]=f2bf(a[3]);
  r[4]=f2bf(b[0]); r[5]=f2bf(b[1]); r[6]=f2bf(b[2]); r[7]=f2bf(b[3]);
  return r;
}
__device__ __forceinline__ bf16x8 ldfrag(const float* base, size_t eo){
  const float* p = base + eo;
  return pack8(*(const f32x4*)p, *(const f32x4*)(p+4));
}

// ---------------- kernel 0: W fp32 -> bf16 once ------------------------------
__global__ __launch_bounds__(256)
void wconv_kernel(const float* __restrict__ Wq, const float* __restrict__ Wk,
                  const float* __restrict__ Wv, short* __restrict__ wb)
{
  int i = (blockIdx.x*256 + threadIdx.x)*8;
  const float* src = (i < 16384) ? Wq : (i < 32768 ? Wk : Wv);
  int off = i & 16383;
  f32x4 a = *(const f32x4*)(src + off);
  f32x4 b = *(const f32x4*)(src + off + 4);
  *(bf16x8*)(wb + i) = pack8(a, b);
}

// ---------------- kernel 1: K/V projections -> ws images (bf16) --------------
// z=1: Kh 32KB images [128 rows]: chunk(r,c8)=r*16+(c8^(r&7)).
// z=2: Vh^T 32KB images [d][c8 0..15]: chunk(d,c8)=d*16+(c8^(d&7)).
// (Q projection moved into attn prologue - no reuse across blocks.)
__global__ __launch_bounds__(256)
void proj_kernel(const float* __restrict__ k, const float* __restrict__ v,
                 const float* __restrict__ bk, const float* __restrict__ bv,
                 const short* __restrict__ wb, short* __restrict__ ws)
{
  __shared__ __align__(16) short T[TB*136];    // [s_local][h] bounce (z==1)
  __shared__ __align__(16) short VT[HD*72];    // [h][s_local] bounce (z==2)

  const int z = blockIdx.y + 1;                // 1=K, 2=V
  const float* x  = (z==1) ? k  : v;
  const float* bb = (z==1) ? bk : bv;
  const short* W  = wb + (size_t)z*HD*HD;

  const int tid = threadIdx.x;
  const int w = tid>>6, l = tid&63, li = l&15, g = l>>4;
  const int bx = blockIdx.x;                   // 64-row tile id (b = bx>>5)
  const int rowbase = bx*TB + w*16;

  bf16x8 afr[4];
  const float* xr = x + (size_t)(rowbase+li)*HD + g*8;
  #pragma unroll
  for (int ks=0; ks<4; ks++) afr[ks] = ldfrag(xr, (size_t)ks*32);

  f32x4 acc[8];
  #pragma unroll
  for (int ct=0; ct<8; ct++) acc[ct] = (f32x4){0.f,0.f,0.f,0.f};
  #pragma unroll
  for (int ct=0; ct<8; ct++){
    #pragma unroll
    for (int ks=0; ks<4; ks++){
      bf16x8 bfr = *(const bf16x8*)(W + (size_t)(ct*16+li)*HD + ks*32 + g*8);
      acc[ct] = MFMA(afr[ks], bfr, acc[ct]);
    }
  }

  const int img  = (bx>>1);                    // 128-row image id
  const int half = bx & 1;                     // which 64-row half

  if (z == 1){
    #pragma unroll
    for (int ct=0; ct<8; ct++){
      float bias = bb[ct*16+li];
      #pragma unroll
      for (int r=0; r<4; r++)
        T[(w*16+g*4+r)*136 + ct*16+li] = f2bf(acc[ct][r] + bias);
    }
    __syncthreads();
    short* dst = ws + PLANE + (size_t)img*16384;
    #pragma unroll
    for (int it=0; it<4; it++){
      int c = tid + it*256, row = c>>4, c8 = c&15;
      int r128 = half*64 + row;
      int chunk = r128*16 + (c8 ^ (r128&7));
      *(bf16x8*)(dst + chunk*8) = *(const bf16x8*)&T[row*136 + c8*8];
    }
  } else {
    #pragma unroll
    for (int ct=0; ct<8; ct++){
      float bias = bb[ct*16+li];
      #pragma unroll
      for (int r=0; r<4; r++)
        VT[(ct*16+li)*72 + w*16+g*4+r] = f2bf(acc[ct][r] + bias);
    }
    __syncthreads();
    short* dst = ws + 2*PLANE + (size_t)img*16384;
    const int d = tid>>1, hf = tid&1;
    #pragma unroll
    for (int j=0; j<4; j++){
      int c8l = hf*4 + j;
      int c8g = half*8 + c8l;
      int chunk = d*16 + (c8g ^ (d&7));
      *(bf16x8*)(dst + chunk*8) = *(const bf16x8*)&VT[d*72 + c8l*8];
    }
  }
}

// ---------------- kernel 2: fused Q-proj + causal flash attention ------------
// R24 loop (swapped QK^T, lane-local softmax, 1 barrier/iter, 2 blocks/CU).
// Prologue: issue LOADT(0) first (global latency overlaps), compute
// Qh = q@Wq^T via MFMA, transpose through KVL[0] (stride-136 bounce,
// 2-way-conflict-free), read qfr, then WRT(0).
__global__ __launch_bounds__(256, 2)
void attn_kernel(const float* __restrict__ qin, const float* __restrict__ bq,
                 const short* __restrict__ wb, const short* __restrict__ ws,
                 float* __restrict__ out)
{
  __shared__ __align__(16) short KVL[2][16384]; // [buf][K 8192 | V 8192] shorts
  __shared__ __align__(16) short PL[4][16*72];  // per-wave P, padded

  const int bid  = blockIdx.x;                  // 512 blocks
  const int xcd  = bid & 7, slot = bid >> 3;    // slot 0..63
  const int b    = xcd*2 + (slot >> 5);
  const int sl   = slot & 31;
  const int qt   = (slot < 32) ? sl : (31 - sl);  // co-resident pair ~33 iters

  const int tid = threadIdx.x;
  const int w = tid>>6, l = tid&63, li = l&15, g = l>>4;

  const short* KimgB = ws + PLANE   + (size_t)b*(SEQ/128)*16384;
  const short* VimgB = ws + 2*PLANE + (size_t)b*(SEQ/128)*16384;

  const size_t qbase = (size_t)b*SEQ + qt*QB3;
  short* Pw = &PL[w][0];
  const float sc = 0.088388347648318447f;       // 1/sqrt(128)

  // staging regs + macros
  bf16x8 stg[8];
  #define LOADT(kt_) do{                                                     \
    const short* sK = KimgB + (size_t)((kt_)>>1)*16384 + ((kt_)&1)*8192;     \
    const short* sV = VimgB + (size_t)((kt_)>>1)*16384;                      \
    const int vh = ((kt_)&1)*8;                                              \
    _Pragma("unroll")                                                        \
    for (int j=0;j<4;j++) stg[j] = *(const bf16x8*)(sK + (tid + j*256)*8);   \
    _Pragma("unroll")                                                        \
    for (int j=0;j<4;j++){                                                   \
      int i = tid + j*256, d = i>>3, c8s = i&7;                              \
      stg[4+j] = *(const bf16x8*)(sV + (d*16 + vh + c8s)*8);                 \
    }                                                                        \
  }while(0)
  #define WRT(nb_) do{                                                      \
    short* dK = &KVL[nb_][0];                                               \
    short* dV = &KVL[nb_][8192];                                            \
    _Pragma("unroll")                                                       \
    for (int j=0;j<4;j++) *(bf16x8*)(dK + (tid+j*256)*8) = stg[j];          \
    _Pragma("unroll")                                                       \
    for (int j=0;j<4;j++) *(bf16x8*)(dV + (tid+j*256)*8) = stg[4+j];        \
  }while(0)

  LOADT(0);                                     // overlap with Q-proj below

  // ---- prologue: Qh = q @ Wq^T + bq for rows qbase..qbase+63 ----
  bf16x8 qfr[4];
  {
    bf16x8 xa[4];
    const float* xr = qin + (qbase + w*16 + li)*HD + g*8;
    #pragma unroll
    for (int ks=0; ks<4; ks++) xa[ks] = ldfrag(xr, (size_t)ks*32);
    f32x4 qa[8];
    #pragma unroll
    for (int ct=0; ct<8; ct++) qa[ct] = (f32x4){0.f,0.f,0.f,0.f};
    #pragma unroll
    for (int ct=0; ct<8; ct++){
      #pragma unroll
      for (int ks=0; ks<4; ks++){
        bf16x8 wf = *(const bf16x8*)(wb + (size_t)(ct*16+li)*HD + ks*32 + g*8);
        qa[ct] = MFMA(xa[ks], wf, qa[ct]);
      }
    }
    short* T = &KVL[0][0];                      // bounce (64 x 136 shorts)
    #pragma unroll
    for (int ct=0; ct<8; ct++){
      float bias = bq[ct*16+li];
      #pragma unroll
      for (int r=0; r<4; r++)
        T[(w*16+g*4+r)*136 + ct*16+li] = f2bf(qa[ct][r] + bias);
    }
    __syncthreads();
    #pragma unroll
    for (int ks=0; ks<4; ks++)
      qfr[ks] = *(const bf16x8*)&T[(w*16+li)*136 + ks*32 + g*8];
    __syncthreads();                            // all reads done before WRT(0)
  }

  f32x4 oacc[8];
  #pragma unroll
  for (int dt=0; dt<8; dt++) oacc[dt] = (f32x4){0.f,0.f,0.f,0.f};
  float mreg = -1e30f, lreg = 0.f;              // for q-row (w*16 + li)

  WRT(0); __syncthreads();
  int cur = 0;

  for (int kt=0; kt<=qt; kt++){
    const bool pre = (kt < qt);
    if (pre) LOADT(kt+1);

    const short* KL = &KVL[cur][0];
    const short* VL = &KVL[cur][8192];

    // ---- swapped QK^T : lane holds S[q=li][k = ct*16 + g*4 + r], ct<4
    f32x4 st[4];
    #pragma unroll
    for (int ct=0; ct<4; ct++) st[ct] = (f32x4){0.f,0.f,0.f,0.f};
    __builtin_amdgcn_s_setprio(1);
    #pragma unroll
    for (int ct=0; ct<4; ct++){
      const int row = ct*16 + li;               // K row (A-frag)
      #pragma unroll
      for (int ks=0; ks<4; ks++){
        const int chunk = row*16 + ((ks*4 + g) ^ (row&7));
        bf16x8 kfr = *(const bf16x8*)&KL[chunk*8];
        st[ct] = MFMA(kfr, qfr[ks], st[ct]);    // SWAPPED operands
      }
    }
    __builtin_amdgcn_s_setprio(0);

    // ---- lane-local online softmax for q-row (w*16 + li)
    float sv[4][4];
    float pm = -1e30f;
    const bool diag = (kt == qt);
    const int qloc = w*16 + li;
    #pragma unroll
    for (int ct=0; ct<4; ct++){
      #pragma unroll
      for (int r=0; r<4; r++){
        float x = st[ct][r]*sc;
        if (diag && (ct*16 + g*4 + r) > qloc) x = -1e30f;
        sv[ct][r] = x;
        pm = fmaxf(pm, x);
      }
    }
    pm = fmaxf(pm, __shfl_xor(pm, 16));
    pm = fmaxf(pm, __shfl_xor(pm, 32));
    float mn   = fmaxf(mreg, pm);
    float sclq = __expf(mreg - mn);
    mreg = mn;
    float psum = 0.f;
    #pragma unroll
    for (int ct=0; ct<4; ct++){
      #pragma unroll
      for (int r=0; r<4; r++){
        float p = __expf(sv[ct][r] - mn);
        sv[ct][r] = p;
        psum += p;
      }
    }
    psum += __shfl_xor(psum, 16);
    psum += __shfl_xor(psum, 32);
    lreg = lreg*sclq + psum;

    // ---- rescale oacc (rows q = g*4+r: factors live in lanes 0..15)
    float sclo[4];
    #pragma unroll
    for (int r=0; r<4; r++) sclo[r] = __shfl(sclq, g*4 + r);
    #pragma unroll
    for (int dt=0; dt<8; dt++){
      #pragma unroll
      for (int r=0; r<4; r++) oacc[dt][r] *= sclo[r];
    }

    // ---- P -> LDS (4x ds_write_b64), then PV over k 0..63
    #pragma unroll
    for (int c4=0; c4<4; c4++){
      u32x2 pw;
      pw[0] = packbf(sv[c4][0], sv[c4][1]);
      pw[1] = packbf(sv[c4][2], sv[c4][3]);
      *(u32x2*)&Pw[li*72 + c4*16 + g*4] = pw;   // row q=li, k=c4*16+g*4..+3
    }
    __builtin_amdgcn_s_setprio(1);
    #pragma unroll
    for (int ks2=0; ks2<2; ks2++){
      bf16x8 afr = *(const bf16x8*)&Pw[li*72 + ks2*32 + g*8];
      #pragma unroll
      for (int dt=0; dt<8; dt++){
        const int d = dt*16 + li;
        const int chunk = d*8 + ((ks2*4 + g) ^ (d&7));
        bf16x8 bfr = *(const bf16x8*)&VL[chunk*8];
        oacc[dt] = MFMA(afr, bfr, oacc[dt]);
      }
    }
    __builtin_amdgcn_s_setprio(0);

    if (pre) WRT(cur^1);
    __syncthreads();                            // single barrier per iteration
    cur ^= 1;
  } // kt

  // ---- epilogue: fp32 out; lsum for row q=g*4+r from lanes 0..15
  float lso[4];
  #pragma unroll
  for (int r=0; r<4; r++) lso[r] = __shfl(lreg, g*4 + r);
  float* Ob = out + qbase*HD;
  #pragma unroll
  for (int dt=0; dt<8; dt++){
    #pragma unroll
    for (int r=0; r<4; r++){
      Ob[(size_t)(w*16 + g*4 + r)*HD + dt*16 + li] = oacc[dt][r] / lso[r];
    }
  }
  #undef LOADT
  #undef WRT
}

// ---------------- launch -----------------------------------------------------
// d_in = [q, k, v, Wq, bq, Wk, bk, Wv, bv, mask] (confirmed R15).
// ws: (Qh slot unused) | Kimg(32KB x 256) | Vimg | Wbf16 (25.3 MB).
extern "C" void kernel_launch(void* const* d_in, const int* in_sizes, int n_in,
                              void* d_out, int out_size, void* d_ws, size_t ws_size,
                              hipStream_t stream)
{
  short* ws = (short*)d_ws;
  short* wb = ws + 3*PLANE;

  wconv_kernel<<<24, 256, 0, stream>>>(
      (const float*)d_in[3], (const float*)d_in[5], (const float*)d_in[7], wb);

  dim3 pg(BATCH*SEQ/TB, 2);                      // K and V planes only
  proj_kernel<<<pg, 256, 0, stream>>>(
      (const float*)d_in[1], (const float*)d_in[2],
      (const float*)d_in[6], (const float*)d_in[8],
      wb, ws);

  attn_kernel<<<dim3(BATCH*NT3), 256, 0, stream>>>(
      (const float*)d_in[0], (const float*)d_in[4], wb, ws, (float*)d_out);
}